// Round 3
// baseline (447.688 us; speedup 1.0000x reference)
//
#include <hip/hip_runtime.h>
#include <stdint.h>

// Problem constants
#define B_   4
#define S_   2048
#define H_   16
#define D_   64
#define DM_  1024
#define NTOK (B_ * S_)          // 8192 tokens

typedef __attribute__((ext_vector_type(8))) short short8;   // 8 bf16 (4 VGPRs)
typedef __attribute__((ext_vector_type(4))) float floatx4;  // MFMA C/D

__device__ inline unsigned short f2bf(float f) {
  // RNE float -> bf16 (finite inputs)
  unsigned int u = __float_as_uint(f);
  u += 0x7FFFu + ((u >> 16) & 1u);
  return (unsigned short)(u >> 16);
}

__device__ inline floatx4 mfma_bf16(short8 a, short8 b, floatx4 c) {
  return __builtin_amdgcn_mfma_f32_16x16x32_bf16(a, b, c, 0, 0, 0);
}

// pack two fp32 into bf16x2 (RTZ: take high 16 bits of each) — one v_perm_b32
__device__ inline unsigned int pack_bf2(float lo, float hi) {
  return __builtin_amdgcn_perm(__float_as_uint(hi), __float_as_uint(lo), 0x07060302u);
}

// pack two fp32 into bf16x2 with RNE — single HW instruction on gfx950
__device__ inline unsigned int cvt_pk_bf16(float lo, float hi) {
  unsigned int r;
  asm("v_cvt_pk_bf16_f32 %0, %1, %2" : "=v"(r) : "v"(lo), "v"(hi));
  return r;
}

// async global->LDS, 16B per lane; LDS dest = wave-uniform base + lane*16
__device__ inline void gload_lds16(const unsigned short* g, unsigned short* l) {
  __builtin_amdgcn_global_load_lds(
      (const __attribute__((address_space(1))) unsigned int*)g,
      (__attribute__((address_space(3))) unsigned int*)l, 16, 0, 0);
}

// ---------------------------------------------------------------------------
// LDS-tiled weight cast+transpose: w[k][n] fp32 [1024x1024] -> wT[n][k] bf16.
// ---------------------------------------------------------------------------
__global__ __launch_bounds__(256) void wt_kernel(const float* __restrict__ w0,
                                                 const float* __restrict__ w1,
                                                 const float* __restrict__ w2,
                                                 const float* __restrict__ w3,
                                                 unsigned short* __restrict__ o0,
                                                 unsigned short* __restrict__ o1,
                                                 unsigned short* __restrict__ o2,
                                                 unsigned short* __restrict__ o3) {
  __shared__ unsigned short T[64 * 68];   // transposed tile [n][k], stride 68
  const float* w = blockIdx.z == 0 ? w0 : blockIdx.z == 1 ? w1 : blockIdx.z == 2 ? w2 : w3;
  unsigned short* o = blockIdx.z == 0 ? o0 : blockIdx.z == 1 ? o1 : blockIdx.z == 2 ? o2 : o3;
  const int tid = threadIdx.x;
  const int R0 = blockIdx.y * 64;   // k-block
  const int C0 = blockIdx.x * 64;   // n-block
  for (int it = 0; it < 16; it++) {
    int lr = it * 4 + (tid >> 6), lc = tid & 63;
    T[lc * 68 + lr] = f2bf(w[(size_t)(R0 + lr) * 1024 + C0 + lc]);
  }
  __syncthreads();
  for (int it = 0; it < 2; it++) {
    int orow = it * 32 + (tid >> 3), oc = (tid & 7) * 8;
    union { ushort4 h[2]; short8 v8; } u;
    u.h[0] = *(const ushort4*)(T + orow * 68 + oc);
    u.h[1] = *(const ushort4*)(T + orow * 68 + oc + 4);
    *(short8*)(o + (size_t)(C0 + orow) * 1024 + R0 + oc) = u.v8;
  }
}

// ---------------------------------------------------------------------------
// Fused cast+projection GEMM, all 3 projections in ONE dispatch (grid.z=3):
//   C[8192,128nb] = cast_bf16(A_fp32[8192,1024]) x BT[1024,1024]^T
// A is staged fp32 via global_load_lds (16 KB/tile) and converted to bf16
// fragments with RNE v_cvt_pk_bf16_f32 at frag-assembly time — removes the
// separate cast kernels and their 48 MB round-trips.
//
// LDS layout is CHUNK-MAJOR (slot = chunk*128 + row): frag reads then have
// lane-stride 16B -> 2-way bank aliasing (free), vs the m97 row-major layout
// whose reads were 8-way conflicted (m98: 1.7e7 conflicts). Staging stays
// wave-linear as global_load_lds requires; the chunk<->row math moves to the
// per-lane GLOBAL address (guide §5 pre-swizzled-source pattern).
//
// z=0: Q x wqT -> qP  (scale = log2e/sqrt(dk), MODE 0 scatter [B,H,S,64])
// z=1: K x wkT -> kP  (MODE 0)
// z=2: V x wvT -> vTg (MODE 2 scatter [B,H,64,S] with sigma permutation)
// XCD swizzle: blockIdx.x (== dispatch id % 8) picks the m-panel group.
// ---------------------------------------------------------------------------
__global__ __launch_bounds__(256) void proj_kernel(
    const float* __restrict__ Qf, const float* __restrict__ Kf,
    const float* __restrict__ Vf,
    const unsigned short* __restrict__ wqT, const unsigned short* __restrict__ wkT,
    const unsigned short* __restrict__ wvT,
    unsigned short* __restrict__ qP, unsigned short* __restrict__ kP,
    unsigned short* __restrict__ vTg, float sc) {
  constexpr int K = 1024;
  __shared__ __align__(16) float          As[8 * 128 * 4];   // 16 KB fp32, chunk-major
  __shared__ __align__(16) unsigned short Bs[4 * 128 * 8];   // 8 KB bf16, chunk-major

  const int z = blockIdx.z;
  const float* A           = z == 0 ? Qf  : z == 1 ? Kf  : Vf;
  const unsigned short* BT = z == 0 ? wqT : z == 1 ? wkT : wvT;
  unsigned short* Cout     = z == 0 ? qP  : z == 1 ? kP  : vTg;
  const float scale        = z == 0 ? sc : 1.0f;
  const int mode           = (z == 2) ? 2 : 0;

  const int tid  = threadIdx.x;
  const int wave = tid >> 6, lane = tid & 63;
  const int quad = lane >> 4, l16 = lane & 15;
  const int wm = wave >> 1, wn = wave & 1;
  // XCD-aware remap (bijective on 8x64 grid)
  const int mb = blockIdx.x * 8 + (blockIdx.y >> 3);   // 0..63
  const int nb = blockIdx.y & 7;                        // 0..7
  const int m0 = mb * 128, n0 = nb * 128;

  floatx4 acc[4][4] = {};

  for (int k0 = 0; k0 < K; k0 += 32) {
    // stage A fp32: 1024 x 16B slots; slot si = c*128+r  (c: 4-float chunk)
    for (int p = 0; p < 4; p++) {
      int si = p * 256 + tid;
      int r = si & 127, c = si >> 7;
      gload_lds16((const unsigned short*)(A + (size_t)(m0 + r) * K + k0 + c * 4),
                  (unsigned short*)As + (size_t)(p * 256 + wave * 64) * 8);
    }
    // stage B bf16: 512 x 16B slots; slot si = c*128+r  (c: 8-bf16 chunk)
    for (int p = 0; p < 2; p++) {
      int si = p * 256 + tid;
      int r = si & 127, c = si >> 7;
      gload_lds16(BT + (size_t)(n0 + r) * K + k0 + c * 8,
                  Bs + (size_t)(p * 256 + wave * 64) * 8);
    }
    __syncthreads();

    short8 af[4], bfr[4];
    for (int f = 0; f < 4; f++) {
      int ra = wm * 64 + f * 16 + l16;
      float4 a0 = *(const float4*)(As + (2 * quad) * 512 + ra * 4);
      float4 a1 = *(const float4*)(As + (2 * quad + 1) * 512 + ra * 4);
      union { unsigned int u[4]; short8 s8; } pk;
      pk.u[0] = cvt_pk_bf16(a0.x, a0.y);
      pk.u[1] = cvt_pk_bf16(a0.z, a0.w);
      pk.u[2] = cvt_pk_bf16(a1.x, a1.y);
      pk.u[3] = cvt_pk_bf16(a1.z, a1.w);
      af[f] = pk.s8;
      int rb = wn * 64 + f * 16 + l16;
      bfr[f] = *(const short8*)(Bs + ((size_t)quad * 128 + rb) * 8);
    }
    for (int fm = 0; fm < 4; fm++)
      for (int fn = 0; fn < 4; fn++)
        acc[fm][fn] = mfma_bf16(af[fm], bfr[fn], acc[fm][fn]);
    __syncthreads();
  }

  for (int fm = 0; fm < 4; fm++)
    for (int fn = 0; fn < 4; fn++)
      for (int r = 0; r < 4; r++) {
        int gm = m0 + wm * 64 + fm * 16 + quad * 4 + r;
        int gn = n0 + wn * 64 + fn * 16 + l16;
        float val = acc[fm][fn][r] * scale;
        int b = gm >> 11, s = gm & 2047;
        int h = gn >> 6,  d = gn & 63;
        if (mode == 0) {
          Cout[((size_t)((b * H_ + h) * S_ + s) << 6) + d] = f2bf(val);
        } else {
          int p = ((s & 63) >> 4) + (s & 15) * 4;   // inv_sigma within 64-block
          Cout[(((size_t)(b * H_ + h) * 64 + d) << 11) + (s & ~63) + p] = f2bf(val);
        }
      }
}

// ---------------------------------------------------------------------------
// bf16 GEMM: C[8192,1024] = A[8192,1024] x BT[1024,1024]^T  (output proj)
// MODE 1: fp32 row-major out. Chunk-major LDS (2-way banks, see proj_kernel).
// ---------------------------------------------------------------------------
template <int MODE>
__global__ __launch_bounds__(256) void gemm_bt_kernel(const unsigned short* __restrict__ A,
                                                      const unsigned short* __restrict__ BT,
                                                      void* __restrict__ Cout,
                                                      float scale) {
  constexpr int K = 1024;
  __shared__ __align__(16) unsigned short As[4 * 128 * 8];  // 8 KB, chunk-major
  __shared__ __align__(16) unsigned short Bs[4 * 128 * 8];  // 8 KB, chunk-major

  const int tid  = threadIdx.x;
  const int wave = tid >> 6, lane = tid & 63;
  const int quad = lane >> 4, l16 = lane & 15;
  const int wm = wave >> 1, wn = wave & 1;
  // XCD-aware remap (bijective on 8x64 grid)
  const int mb = blockIdx.x * 8 + (blockIdx.y >> 3);   // 0..63
  const int nb = blockIdx.y & 7;                        // 0..7
  const int m0 = mb * 128, n0 = nb * 128;

  floatx4 acc[4][4] = {};

  for (int k0 = 0; k0 < K; k0 += 32) {
    for (int p = 0; p < 2; p++) {
      int si = p * 256 + tid;
      int r = si & 127, c = si >> 7;
      gload_lds16(A  + (size_t)(m0 + r) * K + k0 + c * 8,
                  As + (size_t)(p * 256 + wave * 64) * 8);
      gload_lds16(BT + (size_t)(n0 + r) * K + k0 + c * 8,
                  Bs + (size_t)(p * 256 + wave * 64) * 8);
    }
    __syncthreads();

    short8 af[4], bfr[4];
    for (int f = 0; f < 4; f++) {
      af[f]  = *(const short8*)(As + ((size_t)quad * 128 + wm * 64 + f * 16 + l16) * 8);
      bfr[f] = *(const short8*)(Bs + ((size_t)quad * 128 + wn * 64 + f * 16 + l16) * 8);
    }
    for (int fm = 0; fm < 4; fm++)
      for (int fn = 0; fn < 4; fn++)
        acc[fm][fn] = mfma_bf16(af[fm], bfr[fn], acc[fm][fn]);
    __syncthreads();
  }

  for (int fm = 0; fm < 4; fm++)
    for (int fn = 0; fn < 4; fn++)
      for (int r = 0; r < 4; r++) {
        int gm = m0 + wm * 64 + fm * 16 + quad * 4 + r;
        int gn = n0 + wn * 64 + fn * 16 + l16;
        float val = acc[fm][fn][r] * scale;
        if (MODE == 0) {
          int b = gm >> 11, s = gm & 2047;
          int h = gn >> 6,  d = gn & 63;
          ((unsigned short*)Cout)[((size_t)((b * H_ + h) * S_ + s) << 6) + d] = f2bf(val);
        } else if (MODE == 1) {
          ((float*)Cout)[((size_t)gm << 10) + gn] = val;
        } else {
          int b = gm >> 11, s = gm & 2047;
          int h = gn >> 6,  d = gn & 63;
          int p = ((s & 63) >> 4) + (s & 15) * 4;   // inv_sigma within 64-block
          ((unsigned short*)Cout)[(((size_t)(b * H_ + h) * 64 + d) << 11) + (s & ~63) + p] = f2bf(val);
        }
      }
}

// ---------------------------------------------------------------------------
// Flash attention v4: no-max exp2 softmax, V pre-transposed+sigma-permuted
// ([B,H,64,S]), K and V^T staged via XOR-swizzled global_load_lds.
// Double-buffered K/V LDS, one barrier per iter; raw v_exp_f32.
// ---------------------------------------------------------------------------
__global__ __launch_bounds__(512, 4) void attn_kernel(const unsigned short* __restrict__ q,
                                                      const unsigned short* __restrict__ k,
                                                      const unsigned short* __restrict__ vT,
                                                      unsigned short* __restrict__ X) {
  __shared__ unsigned short Ks[2][64 * 64];   // 2 x 8 KB, XOR-swizzled chunks
  __shared__ unsigned short Vt[2][64 * 64];   // 2 x 8 KB, XOR-swizzled chunks
  __shared__ unsigned short Ps[8][16 * 72];   // 18 KB, per-wave P tile, padded

  const int tid  = threadIdx.x;
  const int wave = tid >> 6, lane = tid & 63;
  const int quad = lane >> 4, l16 = lane & 15;
  // XCD-aware remap (bijective on 8x64 grid)
  const int bh = blockIdx.x * 8 + (blockIdx.y >> 3);
  const int q0 = (blockIdx.y & 7) * 256;

  const unsigned short* qh = q  + (size_t)bh * S_ * 64;
  const unsigned short* kh = k  + (size_t)bh * S_ * 64;
  const unsigned short* vh = vT + (size_t)bh * 64 * S_;   // [d][s']

  // staging pattern: 512 lanes x 16B = full 8 KB tile; chunk c of row r at
  // slot c^(r&7)
  const int sr  = tid >> 3;
  const int sgc = (tid & 7) ^ (sr & 7);

  // Q fragments (A-layout), resident: 2 qt x 2 k-chunks
  short8 qf[2][2];
  for (int qt = 0; qt < 2; qt++) {
    int row = q0 + wave * 32 + qt * 16 + l16;
    for (int kk = 0; kk < 2; kk++)
      qf[qt][kk] = *(const short8*)(qh + (size_t)row * 64 + kk * 32 + quad * 8);
  }

  // ones-column B-frag: B[k][n] = (n==0) ? 1 : 0
  short8 onesb = {};
  if (l16 == 0)
    for (int e = 0; e < 8; e++) onesb[e] = (short)0x3F80;

  const floatx4 fz = {};   // hoisted zero for per-iter score accumulators
  floatx4 O[2][4] = {};
  floatx4 lacc[2] = {};

  // prologue: stage tile 0 into buffer 0
  gload_lds16(kh + (size_t)sr * 64 + sgc * 8,       Ks[0] + (size_t)(wave * 64) * 8);
  gload_lds16(vh + (size_t)sr * S_ + 0 + sgc * 8,   Vt[0] + (size_t)(wave * 64) * 8);

  int cur = 0;
  for (int j0 = 0; j0 < S_; j0 += 64) {
    // One barrier per iter: drains last iter's loads (covered by the whole
    // compute phase) and orders reads of buf[cur^1] before its overwrite.
    __syncthreads();

    // issue next tile's stage early (overlaps with this iter's compute)
    if (j0 + 64 < S_) {
      int nxt = cur ^ 1;
      gload_lds16(kh + (size_t)(j0 + 64 + sr) * 64 + sgc * 8,
                  Ks[nxt] + (size_t)(wave * 64) * 8);
      gload_lds16(vh + (size_t)sr * S_ + (j0 + 64) + sgc * 8,
                  Vt[nxt] + (size_t)(wave * 64) * 8);
    }

    // K frags (B-layout: n=j=jf*16+l16, k=d): undo swizzle
    short8 kf[4][2];
    for (int jf = 0; jf < 4; jf++)
      for (int kk = 0; kk < 2; kk++) {
        int sl = (kk * 4 + quad) ^ (l16 & 7);
        kf[jf][kk] = *(const short8*)(Ks[cur] + (jf * 16 + l16) * 64 + sl * 8);
      }

    unsigned short* pw = Ps[wave];
    short8 pa[2][2];
    for (int qt = 0; qt < 2; qt++) {
      floatx4 s[4];
      for (int jf = 0; jf < 4; jf++) {
        s[jf] = mfma_bf16(qf[qt][0], kf[jf][0], fz);
        s[jf] = mfma_bf16(qf[qt][1], kf[jf][1], s[jf]);
      }
      // p = exp2(score) (q pre-scaled by log2e/sqrt(dk)); raw v_exp_f32,
      // RTZ-pack to bf16. Lane's 4 jf-values land at sigma positions 4*l16+jf.
      for (int r = 0; r < 4; r++) {
        float e0 = __builtin_amdgcn_exp2f(s[0][r]);
        float e1 = __builtin_amdgcn_exp2f(s[1][r]);
        float e2 = __builtin_amdgcn_exp2f(s[2][r]);
        float e3 = __builtin_amdgcn_exp2f(s[3][r]);
        uint2 pk;
        pk.x = pack_bf2(e0, e1);
        pk.y = pack_bf2(e2, e3);
        *(uint2*)(pw + (quad * 4 + r) * 72 + l16 * 4) = pk;
      }
      pa[qt][0] = *(const short8*)(pw + l16 * 72 + quad * 8);
      pa[qt][1] = *(const short8*)(pw + l16 * 72 + 32 + quad * 8);
      lacc[qt] = mfma_bf16(pa[qt][0], onesb, lacc[qt]);
      lacc[qt] = mfma_bf16(pa[qt][1], onesb, lacc[qt]);
    }

    // PV: V frags loaded per-df (8 VGPRs live at a time)
    for (int df = 0; df < 4; df++) {
      int sl0 = quad ^ (l16 & 7);
      int sl1 = (4 + quad) ^ (l16 & 7);
      short8 v0 = *(const short8*)(Vt[cur] + (df * 16 + l16) * 64 + sl0 * 8);
      short8 v1 = *(const short8*)(Vt[cur] + (df * 16 + l16) * 64 + sl1 * 8);
      for (int qt = 0; qt < 2; qt++) {
        O[qt][df] = mfma_bf16(pa[qt][0], v0, O[qt][df]);
        O[qt][df] = mfma_bf16(pa[qt][1], v1, O[qt][df]);
      }
    }
    cur ^= 1;
  }

  // epilogue: l lives in lane quad*16 (col 0), reg r; broadcast, divide, store
  const int b = bh >> 4, h = bh & 15;
  for (int qt = 0; qt < 2; qt++)
    for (int r = 0; r < 4; r++) {
      float lsum = __shfl(lacc[qt][r], (lane & 48));
      float inv = 1.0f / lsum;
      int row = q0 + wave * 32 + qt * 16 + quad * 4 + r;
      unsigned short* dst = X + ((size_t)(b * S_ + row) << 10) + h * 64;
      for (int df = 0; df < 4; df++)
        dst[df * 16 + l16] = f2bf(O[qt][df][r] * inv);
    }
}

// ---------------------------------------------------------------------------
extern "C" void kernel_launch(void* const* d_in, const int* in_sizes, int n_in,
                              void* d_out, int out_size, void* d_ws, size_t ws_size,
                              hipStream_t stream) {
  const float* Q  = (const float*)d_in[0];
  const float* K  = (const float*)d_in[1];
  const float* V  = (const float*)d_in[2];
  const float* wq = (const float*)d_in[3];
  const float* wk = (const float*)d_in[4];
  const float* wv = (const float*)d_in[5];
  const float* wo = (const float*)d_in[6];

  char* ws = (char*)d_ws;
  unsigned short* buf0 = (unsigned short*)ws;                        // 16 MB (attn X)
  unsigned short* wqT  = (unsigned short*)(ws + (size_t)(16 << 20));
  unsigned short* wkT  = (unsigned short*)(ws + (size_t)(18 << 20));
  unsigned short* wvT  = (unsigned short*)(ws + (size_t)(20 << 20));
  unsigned short* woT  = (unsigned short*)(ws + (size_t)(22 << 20));
  unsigned short* qP   = (unsigned short*)(ws + (size_t)(24 << 20));  // [B,H,S,64]
  unsigned short* kP   = (unsigned short*)(ws + (size_t)(40 << 20));  // [B,H,S,64]
  unsigned short* vTg  = (unsigned short*)(ws + (size_t)(56 << 20));  // [B,H,64,S] sigma

  const float SC = 0.18033688011112043f;   // log2(e) / sqrt(64), folded into q

  wt_kernel<<<dim3(16, 16, 4), dim3(256), 0, stream>>>(wq, wk, wv, wo, wqT, wkT, wvT, woT);

  proj_kernel<<<dim3(8, 64, 3), dim3(256), 0, stream>>>(Q, K, V, wqT, wkT, wvT,
                                                        qP, kP, vTg, SC);

  attn_kernel<<<dim3(8, 64), dim3(512), 0, stream>>>(qP, kP, vTg, buf0);

  gemm_bt_kernel<1><<<dim3(8, 64), dim3(256), 0, stream>>>(buf0, woT, (float*)d_out, 1.0f);
}

// Round 4
// 358.109 us; speedup vs baseline: 1.2501x; 1.2501x over previous
//
#include <hip/hip_runtime.h>
#include <stdint.h>

// Problem constants
#define B_   4
#define S_   2048
#define H_   16
#define D_   64
#define DM_  1024
#define NTOK (B_ * S_)          // 8192 tokens

typedef __attribute__((ext_vector_type(8))) short short8;   // 8 bf16 (4 VGPRs)
typedef __attribute__((ext_vector_type(4))) float floatx4;  // MFMA C/D

__device__ inline unsigned short f2bf(float f) {
  // RNE float -> bf16 (finite inputs)
  unsigned int u = __float_as_uint(f);
  u += 0x7FFFu + ((u >> 16) & 1u);
  return (unsigned short)(u >> 16);
}

__device__ inline floatx4 mfma_bf16(short8 a, short8 b, floatx4 c) {
  return __builtin_amdgcn_mfma_f32_16x16x32_bf16(a, b, c, 0, 0, 0);
}

// pack two fp32 into bf16x2 (RTZ: take high 16 bits of each) — one v_perm_b32
__device__ inline unsigned int pack_bf2(float lo, float hi) {
  return __builtin_amdgcn_perm(__float_as_uint(hi), __float_as_uint(lo), 0x07060302u);
}

// pack two fp32 into bf16x2 with RNE — single HW instruction on gfx950
__device__ inline unsigned int cvt_pk_bf16(float lo, float hi) {
  unsigned int r;
  asm("v_cvt_pk_bf16_f32 %0, %1, %2" : "=v"(r) : "v"(lo), "v"(hi));
  return r;
}

// async global->LDS, 16B per lane; LDS dest = wave-uniform base + lane*16
__device__ inline void gload_lds16(const unsigned short* g, unsigned short* l) {
  __builtin_amdgcn_global_load_lds(
      (const __attribute__((address_space(1))) unsigned int*)g,
      (__attribute__((address_space(3))) unsigned int*)l, 16, 0, 0);
}

// ---------------------------------------------------------------------------
// LDS-tiled weight cast+transpose: w[k][n] fp32 [1024x1024] -> wT[n][k] bf16.
// ---------------------------------------------------------------------------
__global__ __launch_bounds__(256) void wt_kernel(const float* __restrict__ w0,
                                                 const float* __restrict__ w1,
                                                 const float* __restrict__ w2,
                                                 const float* __restrict__ w3,
                                                 unsigned short* __restrict__ o0,
                                                 unsigned short* __restrict__ o1,
                                                 unsigned short* __restrict__ o2,
                                                 unsigned short* __restrict__ o3) {
  __shared__ unsigned short T[64 * 68];   // transposed tile [n][k], stride 68
  const float* w = blockIdx.z == 0 ? w0 : blockIdx.z == 1 ? w1 : blockIdx.z == 2 ? w2 : w3;
  unsigned short* o = blockIdx.z == 0 ? o0 : blockIdx.z == 1 ? o1 : blockIdx.z == 2 ? o2 : o3;
  const int tid = threadIdx.x;
  const int R0 = blockIdx.y * 64;   // k-block
  const int C0 = blockIdx.x * 64;   // n-block
  for (int it = 0; it < 16; it++) {
    int lr = it * 4 + (tid >> 6), lc = tid & 63;
    T[lc * 68 + lr] = f2bf(w[(size_t)(R0 + lr) * 1024 + C0 + lc]);
  }
  __syncthreads();
  for (int it = 0; it < 2; it++) {
    int orow = it * 32 + (tid >> 3), oc = (tid & 7) * 8;
    union { ushort4 h[2]; short8 v8; } u;
    u.h[0] = *(const ushort4*)(T + orow * 68 + oc);
    u.h[1] = *(const ushort4*)(T + orow * 68 + oc + 4);
    *(short8*)(o + (size_t)(C0 + orow) * 1024 + R0 + oc) = u.v8;
  }
}

// ---------------------------------------------------------------------------
// LDS layouts (lesson from R3: global_load_lds forces wave-linear LDS dests,
// so swizzles must be permutations of the per-lane GLOBAL address that stay
// coalesced — rule #21: both-sides-or-neither).
//
// A fp32 tile [128r x 32 fp32] = 128B/row = 8 x 16B chunks. Row-major would be
// a 16-WAY read conflict (row stride = full bank cycle). XOR-swizzle: chunk gc
// of row r stored at slot gc^(r&7); staging lane si: r=si>>3, j=si&7,
// gc=j^(r&7) -> 8 lanes cover one 128B row (permuted) = fully coalesced.
// Frag read slot (2q)^(ra&7): 16 lanes -> 8 distinct slots -> 2-way = free.
//
// B bf16 tile [128r x 32 bf16] = 64B/row; pair rows into 64 super-rows of
// 128B (8 chunks: h = (r&1)*4 + c), swizzle h^(R&7). Staging: 8 lanes = 2
// rows x 64B segments (same coalescing as proven m97 pattern). Frag read:
// 2-way (was 8-way in m97 row-major).
// ---------------------------------------------------------------------------

// ---------------------------------------------------------------------------
// Fused cast+projection GEMM, all 3 projections in ONE dispatch (grid.z=3):
//   C[8192,128nb] = cast_bf16(A_fp32[8192,1024]) x BT[1024,1024]^T
// A staged fp32 via global_load_lds, converted to bf16 frags with RNE
// v_cvt_pk_bf16_f32 — no separate cast kernels / round-trips.
// z=0: Q x wqT -> qP (scale folded), z=1: K x wkT -> kP, z=2: V x wvT -> vTg
// (MODE 2 scatter [B,H,64,S] with sigma permutation).
// XCD swizzle: blockIdx.x (== dispatch id % 8) picks the m-panel group.
// ---------------------------------------------------------------------------
__global__ __launch_bounds__(256) void proj_kernel(
    const float* __restrict__ Qf, const float* __restrict__ Kf,
    const float* __restrict__ Vf,
    const unsigned short* __restrict__ wqT, const unsigned short* __restrict__ wkT,
    const unsigned short* __restrict__ wvT,
    unsigned short* __restrict__ qP, unsigned short* __restrict__ kP,
    unsigned short* __restrict__ vTg, float sc) {
  constexpr int K = 1024;
  __shared__ __align__(16) float          As[128 * 32];   // 16 KB fp32, XOR-swizzled
  __shared__ __align__(16) unsigned short Bs[128 * 32];   // 8 KB bf16, XOR-swizzled

  const int z = blockIdx.z;
  const float* A           = z == 0 ? Qf  : z == 1 ? Kf  : Vf;
  const unsigned short* BT = z == 0 ? wqT : z == 1 ? wkT : wvT;
  unsigned short* Cout     = z == 0 ? qP  : z == 1 ? kP  : vTg;
  const float scale        = z == 0 ? sc : 1.0f;
  const int mode           = (z == 2) ? 2 : 0;

  const int tid  = threadIdx.x;
  const int wave = tid >> 6, lane = tid & 63;
  const int quad = lane >> 4, l16 = lane & 15;
  const int wm = wave >> 1, wn = wave & 1;
  // XCD-aware remap (bijective on 8x64 grid)
  const int mb = blockIdx.x * 8 + (blockIdx.y >> 3);   // 0..63
  const int nb = blockIdx.y & 7;                        // 0..7
  const int m0 = mb * 128, n0 = nb * 128;

  floatx4 acc[4][4] = {};

  for (int k0 = 0; k0 < K; k0 += 32) {
    // stage A fp32: 1024 slots; slot si holds chunk (si&7)^(r&7) of row r=si>>3
    for (int p = 0; p < 4; p++) {
      int si = p * 256 + tid;
      int r = si >> 3;
      int gc = (si & 7) ^ (r & 7);
      gload_lds16((const unsigned short*)(A + (size_t)(m0 + r) * K + k0 + gc * 4),
                  (unsigned short*)As + (size_t)(p * 256 + wave * 64) * 8);
    }
    // stage B bf16: 512 slots; super-row R=si>>3 (2 rows), slot j=si&7 holds
    // chunk gc=j^(R&7) -> row R*2+(gc>>2), col chunk gc&3
    for (int p = 0; p < 2; p++) {
      int si = p * 256 + tid;
      int R = si >> 3;
      int gc = (si & 7) ^ (R & 7);
      gload_lds16(BT + (size_t)(n0 + R * 2 + (gc >> 2)) * K + k0 + (gc & 3) * 8,
                  Bs + (size_t)(p * 256 + wave * 64) * 8);
    }
    __syncthreads();

    short8 af[4], bfr[4];
    for (int f = 0; f < 4; f++) {
      int ra = wm * 64 + f * 16 + l16;
      int swa = ra & 7;
      float4 a0 = *(const float4*)(As + ra * 32 + ((2 * quad) ^ swa) * 4);
      float4 a1 = *(const float4*)(As + ra * 32 + ((2 * quad + 1) ^ swa) * 4);
      union { unsigned int u[4]; short8 s8; } pk;
      pk.u[0] = cvt_pk_bf16(a0.x, a0.y);
      pk.u[1] = cvt_pk_bf16(a0.z, a0.w);
      pk.u[2] = cvt_pk_bf16(a1.x, a1.y);
      pk.u[3] = cvt_pk_bf16(a1.z, a1.w);
      af[f] = pk.s8;
      int rb = wn * 64 + f * 16 + l16;
      int slb = (((rb & 1) * 4 + quad) ^ ((rb >> 1) & 7));
      bfr[f] = *(const short8*)(Bs + (rb >> 1) * 64 + slb * 8);
    }
    for (int fm = 0; fm < 4; fm++)
      for (int fn = 0; fn < 4; fn++)
        acc[fm][fn] = mfma_bf16(af[fm], bfr[fn], acc[fm][fn]);
    __syncthreads();
  }

  for (int fm = 0; fm < 4; fm++)
    for (int fn = 0; fn < 4; fn++)
      for (int r = 0; r < 4; r++) {
        int gm = m0 + wm * 64 + fm * 16 + quad * 4 + r;
        int gn = n0 + wn * 64 + fn * 16 + l16;
        float val = acc[fm][fn][r] * scale;
        int b = gm >> 11, s = gm & 2047;
        int h = gn >> 6,  d = gn & 63;
        if (mode == 0) {
          Cout[((size_t)((b * H_ + h) * S_ + s) << 6) + d] = f2bf(val);
        } else {
          int p = ((s & 63) >> 4) + (s & 15) * 4;   // inv_sigma within 64-block
          Cout[(((size_t)(b * H_ + h) * 64 + d) << 11) + (s & ~63) + p] = f2bf(val);
        }
      }
}

// ---------------------------------------------------------------------------
// bf16 GEMM: C[8192,1024] = A[8192,1024] x BT[1024,1024]^T  (output proj)
// MODE 1: fp32 row-major out. Both operands use the B-tile swizzled layout.
// ---------------------------------------------------------------------------
template <int MODE>
__global__ __launch_bounds__(256) void gemm_bt_kernel(const unsigned short* __restrict__ A,
                                                      const unsigned short* __restrict__ BT,
                                                      void* __restrict__ Cout,
                                                      float scale) {
  constexpr int K = 1024;
  __shared__ __align__(16) unsigned short As[128 * 32];  // 8 KB, XOR-swizzled
  __shared__ __align__(16) unsigned short Bs[128 * 32];  // 8 KB, XOR-swizzled

  const int tid  = threadIdx.x;
  const int wave = tid >> 6, lane = tid & 63;
  const int quad = lane >> 4, l16 = lane & 15;
  const int wm = wave >> 1, wn = wave & 1;
  // XCD-aware remap (bijective on 8x64 grid)
  const int mb = blockIdx.x * 8 + (blockIdx.y >> 3);   // 0..63
  const int nb = blockIdx.y & 7;                        // 0..7
  const int m0 = mb * 128, n0 = nb * 128;

  floatx4 acc[4][4] = {};

  for (int k0 = 0; k0 < K; k0 += 32) {
    for (int p = 0; p < 2; p++) {
      int si = p * 256 + tid;
      int R = si >> 3;
      int gc = (si & 7) ^ (R & 7);
      int r = R * 2 + (gc >> 2), c = gc & 3;
      gload_lds16(A  + (size_t)(m0 + r) * K + k0 + c * 8,
                  As + (size_t)(p * 256 + wave * 64) * 8);
      gload_lds16(BT + (size_t)(n0 + r) * K + k0 + c * 8,
                  Bs + (size_t)(p * 256 + wave * 64) * 8);
    }
    __syncthreads();

    short8 af[4], bfr[4];
    for (int f = 0; f < 4; f++) {
      int ra = wm * 64 + f * 16 + l16;
      int sla = (((ra & 1) * 4 + quad) ^ ((ra >> 1) & 7));
      af[f] = *(const short8*)(As + (ra >> 1) * 64 + sla * 8);
      int rb = wn * 64 + f * 16 + l16;
      int slb = (((rb & 1) * 4 + quad) ^ ((rb >> 1) & 7));
      bfr[f] = *(const short8*)(Bs + (rb >> 1) * 64 + slb * 8);
    }
    for (int fm = 0; fm < 4; fm++)
      for (int fn = 0; fn < 4; fn++)
        acc[fm][fn] = mfma_bf16(af[fm], bfr[fn], acc[fm][fn]);
    __syncthreads();
  }

  for (int fm = 0; fm < 4; fm++)
    for (int fn = 0; fn < 4; fn++)
      for (int r = 0; r < 4; r++) {
        int gm = m0 + wm * 64 + fm * 16 + quad * 4 + r;
        int gn = n0 + wn * 64 + fn * 16 + l16;
        float val = acc[fm][fn][r] * scale;
        if (MODE == 0) {
          int b = gm >> 11, s = gm & 2047;
          int h = gn >> 6,  d = gn & 63;
          ((unsigned short*)Cout)[((size_t)((b * H_ + h) * S_ + s) << 6) + d] = f2bf(val);
        } else if (MODE == 1) {
          ((float*)Cout)[((size_t)gm << 10) + gn] = val;
        } else {
          int b = gm >> 11, s = gm & 2047;
          int h = gn >> 6,  d = gn & 63;
          int p = ((s & 63) >> 4) + (s & 15) * 4;   // inv_sigma within 64-block
          ((unsigned short*)Cout)[(((size_t)(b * H_ + h) * 64 + d) << 11) + (s & ~63) + p] = f2bf(val);
        }
      }
}

// ---------------------------------------------------------------------------
// Flash attention v4: no-max exp2 softmax, V pre-transposed+sigma-permuted
// ([B,H,64,S]), K and V^T staged via XOR-swizzled global_load_lds.
// Double-buffered K/V LDS, one barrier per iter; raw v_exp_f32.
// ---------------------------------------------------------------------------
__global__ __launch_bounds__(512, 4) void attn_kernel(const unsigned short* __restrict__ q,
                                                      const unsigned short* __restrict__ k,
                                                      const unsigned short* __restrict__ vT,
                                                      unsigned short* __restrict__ X) {
  __shared__ unsigned short Ks[2][64 * 64];   // 2 x 8 KB, XOR-swizzled chunks
  __shared__ unsigned short Vt[2][64 * 64];   // 2 x 8 KB, XOR-swizzled chunks
  __shared__ unsigned short Ps[8][16 * 72];   // 18 KB, per-wave P tile, padded

  const int tid  = threadIdx.x;
  const int wave = tid >> 6, lane = tid & 63;
  const int quad = lane >> 4, l16 = lane & 15;
  // XCD-aware remap (bijective on 8x64 grid)
  const int bh = blockIdx.x * 8 + (blockIdx.y >> 3);
  const int q0 = (blockIdx.y & 7) * 256;

  const unsigned short* qh = q  + (size_t)bh * S_ * 64;
  const unsigned short* kh = k  + (size_t)bh * S_ * 64;
  const unsigned short* vh = vT + (size_t)bh * 64 * S_;   // [d][s']

  // staging pattern: 512 lanes x 16B = full 8 KB tile; chunk c of row r at
  // slot c^(r&7)
  const int sr  = tid >> 3;
  const int sgc = (tid & 7) ^ (sr & 7);

  // Q fragments (A-layout), resident: 2 qt x 2 k-chunks
  short8 qf[2][2];
  for (int qt = 0; qt < 2; qt++) {
    int row = q0 + wave * 32 + qt * 16 + l16;
    for (int kk = 0; kk < 2; kk++)
      qf[qt][kk] = *(const short8*)(qh + (size_t)row * 64 + kk * 32 + quad * 8);
  }

  // ones-column B-frag: B[k][n] = (n==0) ? 1 : 0
  short8 onesb = {};
  if (l16 == 0)
    for (int e = 0; e < 8; e++) onesb[e] = (short)0x3F80;

  const floatx4 fz = {};   // hoisted zero for per-iter score accumulators
  floatx4 O[2][4] = {};
  floatx4 lacc[2] = {};

  // prologue: stage tile 0 into buffer 0
  gload_lds16(kh + (size_t)sr * 64 + sgc * 8,       Ks[0] + (size_t)(wave * 64) * 8);
  gload_lds16(vh + (size_t)sr * S_ + 0 + sgc * 8,   Vt[0] + (size_t)(wave * 64) * 8);

  int cur = 0;
  for (int j0 = 0; j0 < S_; j0 += 64) {
    // One barrier per iter: drains last iter's loads (covered by the whole
    // compute phase) and orders reads of buf[cur^1] before its overwrite.
    __syncthreads();

    // issue next tile's stage early (overlaps with this iter's compute)
    if (j0 + 64 < S_) {
      int nxt = cur ^ 1;
      gload_lds16(kh + (size_t)(j0 + 64 + sr) * 64 + sgc * 8,
                  Ks[nxt] + (size_t)(wave * 64) * 8);
      gload_lds16(vh + (size_t)sr * S_ + (j0 + 64) + sgc * 8,
                  Vt[nxt] + (size_t)(wave * 64) * 8);
    }

    // K frags (B-layout: n=j=jf*16+l16, k=d): undo swizzle
    short8 kf[4][2];
    for (int jf = 0; jf < 4; jf++)
      for (int kk = 0; kk < 2; kk++) {
        int sl = (kk * 4 + quad) ^ (l16 & 7);
        kf[jf][kk] = *(const short8*)(Ks[cur] + (jf * 16 + l16) * 64 + sl * 8);
      }

    unsigned short* pw = Ps[wave];
    short8 pa[2][2];
    for (int qt = 0; qt < 2; qt++) {
      floatx4 s[4];
      for (int jf = 0; jf < 4; jf++) {
        s[jf] = mfma_bf16(qf[qt][0], kf[jf][0], fz);
        s[jf] = mfma_bf16(qf[qt][1], kf[jf][1], s[jf]);
      }
      // p = exp2(score) (q pre-scaled by log2e/sqrt(dk)); raw v_exp_f32,
      // RTZ-pack to bf16. Lane's 4 jf-values land at sigma positions 4*l16+jf.
      for (int r = 0; r < 4; r++) {
        float e0 = __builtin_amdgcn_exp2f(s[0][r]);
        float e1 = __builtin_amdgcn_exp2f(s[1][r]);
        float e2 = __builtin_amdgcn_exp2f(s[2][r]);
        float e3 = __builtin_amdgcn_exp2f(s[3][r]);
        uint2 pk;
        pk.x = pack_bf2(e0, e1);
        pk.y = pack_bf2(e2, e3);
        *(uint2*)(pw + (quad * 4 + r) * 72 + l16 * 4) = pk;
      }
      pa[qt][0] = *(const short8*)(pw + l16 * 72 + quad * 8);
      pa[qt][1] = *(const short8*)(pw + l16 * 72 + 32 + quad * 8);
      lacc[qt] = mfma_bf16(pa[qt][0], onesb, lacc[qt]);
      lacc[qt] = mfma_bf16(pa[qt][1], onesb, lacc[qt]);
    }

    // PV: V frags loaded per-df (8 VGPRs live at a time)
    for (int df = 0; df < 4; df++) {
      int sl0 = quad ^ (l16 & 7);
      int sl1 = (4 + quad) ^ (l16 & 7);
      short8 v0 = *(const short8*)(Vt[cur] + (df * 16 + l16) * 64 + sl0 * 8);
      short8 v1 = *(const short8*)(Vt[cur] + (df * 16 + l16) * 64 + sl1 * 8);
      for (int qt = 0; qt < 2; qt++) {
        O[qt][df] = mfma_bf16(pa[qt][0], v0, O[qt][df]);
        O[qt][df] = mfma_bf16(pa[qt][1], v1, O[qt][df]);
      }
    }
    cur ^= 1;
  }

  // epilogue: l lives in lane quad*16 (col 0), reg r; broadcast, divide, store
  const int b = bh >> 4, h = bh & 15;
  for (int qt = 0; qt < 2; qt++)
    for (int r = 0; r < 4; r++) {
      float lsum = __shfl(lacc[qt][r], (lane & 48));
      float inv = 1.0f / lsum;
      int row = q0 + wave * 32 + qt * 16 + quad * 4 + r;
      unsigned short* dst = X + ((size_t)(b * S_ + row) << 10) + h * 64;
      for (int df = 0; df < 4; df++)
        dst[df * 16 + l16] = f2bf(O[qt][df][r] * inv);
    }
}

// ---------------------------------------------------------------------------
extern "C" void kernel_launch(void* const* d_in, const int* in_sizes, int n_in,
                              void* d_out, int out_size, void* d_ws, size_t ws_size,
                              hipStream_t stream) {
  const float* Q  = (const float*)d_in[0];
  const float* K  = (const float*)d_in[1];
  const float* V  = (const float*)d_in[2];
  const float* wq = (const float*)d_in[3];
  const float* wk = (const float*)d_in[4];
  const float* wv = (const float*)d_in[5];
  const float* wo = (const float*)d_in[6];

  char* ws = (char*)d_ws;
  unsigned short* buf0 = (unsigned short*)ws;                        // 16 MB (attn X)
  unsigned short* wqT  = (unsigned short*)(ws + (size_t)(16 << 20));
  unsigned short* wkT  = (unsigned short*)(ws + (size_t)(18 << 20));
  unsigned short* wvT  = (unsigned short*)(ws + (size_t)(20 << 20));
  unsigned short* woT  = (unsigned short*)(ws + (size_t)(22 << 20));
  unsigned short* qP   = (unsigned short*)(ws + (size_t)(24 << 20));  // [B,H,S,64]
  unsigned short* kP   = (unsigned short*)(ws + (size_t)(40 << 20));  // [B,H,S,64]
  unsigned short* vTg  = (unsigned short*)(ws + (size_t)(56 << 20));  // [B,H,64,S] sigma

  const float SC = 0.18033688011112043f;   // log2(e) / sqrt(64), folded into q

  wt_kernel<<<dim3(16, 16, 4), dim3(256), 0, stream>>>(wq, wk, wv, wo, wqT, wkT, wvT, woT);

  proj_kernel<<<dim3(8, 64, 3), dim3(256), 0, stream>>>(Q, K, V, wqT, wkT, wvT,
                                                        qP, kP, vTg, SC);

  attn_kernel<<<dim3(8, 64), dim3(512), 0, stream>>>(qP, kP, vTg, buf0);

  gemm_bt_kernel<1><<<dim3(8, 64), dim3(256), 0, stream>>>(buf0, woT, (float*)d_out, 1.0f);
}

// Round 5
// 352.150 us; speedup vs baseline: 1.2713x; 1.0169x over previous
//
#include <hip/hip_runtime.h>
#include <stdint.h>

// Problem constants
#define B_   4
#define S_   2048
#define H_   16
#define D_   64
#define DM_  1024
#define NTOK (B_ * S_)          // 8192 tokens

typedef __attribute__((ext_vector_type(8))) short short8;   // 8 bf16 (4 VGPRs)
typedef __attribute__((ext_vector_type(4))) float floatx4;  // MFMA C/D

__device__ inline unsigned short f2bf(float f) {
  // RNE float -> bf16 (finite inputs)
  unsigned int u = __float_as_uint(f);
  u += 0x7FFFu + ((u >> 16) & 1u);
  return (unsigned short)(u >> 16);
}

__device__ inline floatx4 mfma_bf16(short8 a, short8 b, floatx4 c) {
  return __builtin_amdgcn_mfma_f32_16x16x32_bf16(a, b, c, 0, 0, 0);
}

// pack two fp32 into bf16x2 (RTZ: take high 16 bits of each) — one v_perm_b32
__device__ inline unsigned int pack_bf2(float lo, float hi) {
  return __builtin_amdgcn_perm(__float_as_uint(hi), __float_as_uint(lo), 0x07060302u);
}

// pack two fp32 into bf16x2 with RNE — single HW instruction on gfx950
__device__ inline unsigned int cvt_pk_bf16(float lo, float hi) {
  unsigned int r;
  asm("v_cvt_pk_bf16_f32 %0, %1, %2" : "=v"(r) : "v"(lo), "v"(hi));
  return r;
}

// async global->LDS, 16B per lane; LDS dest = wave-uniform base + lane*16
__device__ inline void gload_lds16(const unsigned short* g, unsigned short* l) {
  __builtin_amdgcn_global_load_lds(
      (const __attribute__((address_space(1))) unsigned int*)g,
      (__attribute__((address_space(3))) unsigned int*)l, 16, 0, 0);
}

// ---------------------------------------------------------------------------
// LDS-tiled weight cast+transpose: w[k][n] fp32 [1024x1024] -> wT[n][k] bf16.
// ---------------------------------------------------------------------------
__global__ __launch_bounds__(256) void wt_kernel(const float* __restrict__ w0,
                                                 const float* __restrict__ w1,
                                                 const float* __restrict__ w2,
                                                 const float* __restrict__ w3,
                                                 unsigned short* __restrict__ o0,
                                                 unsigned short* __restrict__ o1,
                                                 unsigned short* __restrict__ o2,
                                                 unsigned short* __restrict__ o3) {
  __shared__ unsigned short T[64 * 68];   // transposed tile [n][k], stride 68
  const float* w = blockIdx.z == 0 ? w0 : blockIdx.z == 1 ? w1 : blockIdx.z == 2 ? w2 : w3;
  unsigned short* o = blockIdx.z == 0 ? o0 : blockIdx.z == 1 ? o1 : blockIdx.z == 2 ? o2 : o3;
  const int tid = threadIdx.x;
  const int R0 = blockIdx.y * 64;   // k-block
  const int C0 = blockIdx.x * 64;   // n-block
  for (int it = 0; it < 16; it++) {
    int lr = it * 4 + (tid >> 6), lc = tid & 63;
    T[lc * 68 + lr] = f2bf(w[(size_t)(R0 + lr) * 1024 + C0 + lc]);
  }
  __syncthreads();
  for (int it = 0; it < 2; it++) {
    int orow = it * 32 + (tid >> 3), oc = (tid & 7) * 8;
    union { ushort4 h[2]; short8 v8; } u;
    u.h[0] = *(const ushort4*)(T + orow * 68 + oc);
    u.h[1] = *(const ushort4*)(T + orow * 68 + oc + 4);
    *(short8*)(o + (size_t)(C0 + orow) * 1024 + R0 + oc) = u.v8;
  }
}

// ---------------------------------------------------------------------------
// LDS layouts (rule #21: global_load_lds forces wave-linear LDS dests, so
// swizzles are permutations of the per-lane GLOBAL address, kept coalesced).
//
// A fp32 tile [128r x 32 fp32] = 128B/row = 8 x 16B chunks; chunk gc of row r
// at slot gc^(r&7). Staging: 8 lanes cover one 128B row permuted = coalesced.
// Frag read: within a 16-lane group slots are 8 distinct, 2 lanes each = free.
//
// B bf16 tile [128r x 32 bf16]: pair rows into 64 super-rows of 128B
// (chunk h = (r&1)*4 + c), swizzle h^(R&7). Staging: 2x64B segments/8 lanes.
// Frag read: 2-way within 16-lane group = free.
//
// R4 lesson: with these layouts both staging and frag reads are fine, but the
// single-buffered K-loop serially exposed the full staging latency at every
// barrier (MfmaUtil 13 / VALUBusy 13 / HBM 11% — all idle). R5: double-buffer
// the K-loop (attn's proven structure, 109->80us there): barrier at loop top,
// issue next tile into buf^1, compute on buf. Loads drain one full compute
// phase after issue.
// ---------------------------------------------------------------------------

// ---------------------------------------------------------------------------
// Fused cast+projection GEMM, all 3 projections in ONE dispatch (grid.z=3):
//   C[8192,128nb] = cast_bf16(A_fp32[8192,1024]) x BT[1024,1024]^T
// A staged fp32 via global_load_lds, converted to bf16 frags with RNE
// v_cvt_pk_bf16_f32. z=0: Q->qP (scale folded), z=1: K->kP, z=2: V->vTg
// (scatter [B,H,64,S] with sigma permutation).
// XCD swizzle: blockIdx.x (== dispatch id % 8) picks the m-panel group.
// ---------------------------------------------------------------------------
__global__ __launch_bounds__(256) void proj_kernel(
    const float* __restrict__ Qf, const float* __restrict__ Kf,
    const float* __restrict__ Vf,
    const unsigned short* __restrict__ wqT, const unsigned short* __restrict__ wkT,
    const unsigned short* __restrict__ wvT,
    unsigned short* __restrict__ qP, unsigned short* __restrict__ kP,
    unsigned short* __restrict__ vTg, float sc) {
  constexpr int K = 1024;
  __shared__ __align__(16) float          As[2][128 * 32];   // 2 x 16 KB fp32
  __shared__ __align__(16) unsigned short Bs[2][128 * 32];   // 2 x 8 KB bf16

  const int z = blockIdx.z;
  const float* A           = z == 0 ? Qf  : z == 1 ? Kf  : Vf;
  const unsigned short* BT = z == 0 ? wqT : z == 1 ? wkT : wvT;
  unsigned short* Cout     = z == 0 ? qP  : z == 1 ? kP  : vTg;
  const float scale        = z == 0 ? sc : 1.0f;
  const int mode           = (z == 2) ? 2 : 0;

  const int tid  = threadIdx.x;
  const int wave = tid >> 6, lane = tid & 63;
  const int quad = lane >> 4, l16 = lane & 15;
  const int wm = wave >> 1, wn = wave & 1;
  // XCD-aware remap (bijective on 8x64 grid)
  const int mb = blockIdx.x * 8 + (blockIdx.y >> 3);   // 0..63
  const int nb = blockIdx.y & 7;                        // 0..7
  const int m0 = mb * 128, n0 = nb * 128;

  // staging lane geometry (computed once)
  const int srA  = tid >> 3;                 // row for this lane's base slot
  const int sgcA = (tid & 7) ^ (srA & 7);    // A chunk (16B of fp32)
  const int sRB  = tid >> 3;                 // B super-row
  const int sgcB = (tid & 7) ^ (sRB & 7);    // B chunk within super-row

  floatx4 acc[4][4] = {};

#define STAGE_PROJ(k0, buf)                                                        \
  do {                                                                             \
    for (int p = 0; p < 4; p++) {                                                  \
      int r = (p * 256 + tid) >> 3;                                                \
      int gc = ((p * 256 + tid) & 7) ^ (r & 7);                                    \
      gload_lds16((const unsigned short*)(A + (size_t)(m0 + r) * K + (k0) + gc * 4), \
                  (unsigned short*)As[buf] + (size_t)(p * 256 + wave * 64) * 8);   \
    }                                                                              \
    for (int p = 0; p < 2; p++) {                                                  \
      int R = (p * 256 + tid) >> 3;                                                \
      int gc = ((p * 256 + tid) & 7) ^ (R & 7);                                    \
      gload_lds16(BT + (size_t)(n0 + R * 2 + (gc >> 2)) * K + (k0) + (gc & 3) * 8, \
                  Bs[buf] + (size_t)(p * 256 + wave * 64) * 8);                    \
    }                                                                              \
  } while (0)

  // prologue: stage k-tile 0 into buffer 0
  STAGE_PROJ(0, 0);

  int cur = 0;
  for (int k0 = 0; k0 < K; k0 += 32) {
    // One barrier per iter: drains loads issued LAST iter (full compute phase
    // in flight) and orders reads of buf[cur^1] before its overwrite.
    __syncthreads();

    if (k0 + 32 < K) STAGE_PROJ(k0 + 32, cur ^ 1);

    short8 af[4], bfr[4];
    for (int f = 0; f < 4; f++) {
      int ra = wm * 64 + f * 16 + l16;
      int swa = ra & 7;
      float4 a0 = *(const float4*)(As[cur] + ra * 32 + ((2 * quad) ^ swa) * 4);
      float4 a1 = *(const float4*)(As[cur] + ra * 32 + ((2 * quad + 1) ^ swa) * 4);
      union { unsigned int u[4]; short8 s8; } pk;
      pk.u[0] = cvt_pk_bf16(a0.x, a0.y);
      pk.u[1] = cvt_pk_bf16(a0.z, a0.w);
      pk.u[2] = cvt_pk_bf16(a1.x, a1.y);
      pk.u[3] = cvt_pk_bf16(a1.z, a1.w);
      af[f] = pk.s8;
      int rb = wn * 64 + f * 16 + l16;
      int slb = (((rb & 1) * 4 + quad) ^ ((rb >> 1) & 7));
      bfr[f] = *(const short8*)(Bs[cur] + (rb >> 1) * 64 + slb * 8);
    }
    for (int fm = 0; fm < 4; fm++)
      for (int fn = 0; fn < 4; fn++)
        acc[fm][fn] = mfma_bf16(af[fm], bfr[fn], acc[fm][fn]);
    cur ^= 1;
  }
#undef STAGE_PROJ

  for (int fm = 0; fm < 4; fm++)
    for (int fn = 0; fn < 4; fn++)
      for (int r = 0; r < 4; r++) {
        int gm = m0 + wm * 64 + fm * 16 + quad * 4 + r;
        int gn = n0 + wn * 64 + fn * 16 + l16;
        float val = acc[fm][fn][r] * scale;
        int b = gm >> 11, s = gm & 2047;
        int h = gn >> 6,  d = gn & 63;
        if (mode == 0) {
          Cout[((size_t)((b * H_ + h) * S_ + s) << 6) + d] = f2bf(val);
        } else {
          int p = ((s & 63) >> 4) + (s & 15) * 4;   // inv_sigma within 64-block
          Cout[(((size_t)(b * H_ + h) * 64 + d) << 11) + (s & ~63) + p] = f2bf(val);
        }
      }
}

// ---------------------------------------------------------------------------
// bf16 GEMM: C[8192,1024] = A[8192,1024] x BT[1024,1024]^T  (output proj)
// MODE 1: fp32 row-major out. Both operands use the B-tile swizzled layout.
// Double-buffered K-loop (see proj_kernel header).
// ---------------------------------------------------------------------------
template <int MODE>
__global__ __launch_bounds__(256) void gemm_bt_kernel(const unsigned short* __restrict__ A,
                                                      const unsigned short* __restrict__ BT,
                                                      void* __restrict__ Cout,
                                                      float scale) {
  constexpr int K = 1024;
  __shared__ __align__(16) unsigned short As[2][128 * 32];  // 2 x 8 KB
  __shared__ __align__(16) unsigned short Bs[2][128 * 32];  // 2 x 8 KB

  const int tid  = threadIdx.x;
  const int wave = tid >> 6, lane = tid & 63;
  const int quad = lane >> 4, l16 = lane & 15;
  const int wm = wave >> 1, wn = wave & 1;
  // XCD-aware remap (bijective on 8x64 grid)
  const int mb = blockIdx.x * 8 + (blockIdx.y >> 3);   // 0..63
  const int nb = blockIdx.y & 7;                        // 0..7
  const int m0 = mb * 128, n0 = nb * 128;

  floatx4 acc[4][4] = {};

#define STAGE_GEMM(k0, buf)                                                     \
  do {                                                                          \
    for (int p = 0; p < 2; p++) {                                               \
      int si = p * 256 + tid;                                                   \
      int R = si >> 3;                                                          \
      int gc = (si & 7) ^ (R & 7);                                              \
      int r = R * 2 + (gc >> 2), c = gc & 3;                                    \
      gload_lds16(A  + (size_t)(m0 + r) * K + (k0) + c * 8,                     \
                  As[buf] + (size_t)(p * 256 + wave * 64) * 8);                 \
      gload_lds16(BT + (size_t)(n0 + r) * K + (k0) + c * 8,                     \
                  Bs[buf] + (size_t)(p * 256 + wave * 64) * 8);                 \
    }                                                                           \
  } while (0)

  STAGE_GEMM(0, 0);

  int cur = 0;
  for (int k0 = 0; k0 < K; k0 += 32) {
    __syncthreads();

    if (k0 + 32 < K) STAGE_GEMM(k0 + 32, cur ^ 1);

    short8 af[4], bfr[4];
    for (int f = 0; f < 4; f++) {
      int ra = wm * 64 + f * 16 + l16;
      int sla = (((ra & 1) * 4 + quad) ^ ((ra >> 1) & 7));
      af[f] = *(const short8*)(As[cur] + (ra >> 1) * 64 + sla * 8);
      int rb = wn * 64 + f * 16 + l16;
      int slb = (((rb & 1) * 4 + quad) ^ ((rb >> 1) & 7));
      bfr[f] = *(const short8*)(Bs[cur] + (rb >> 1) * 64 + slb * 8);
    }
    for (int fm = 0; fm < 4; fm++)
      for (int fn = 0; fn < 4; fn++)
        acc[fm][fn] = mfma_bf16(af[fm], bfr[fn], acc[fm][fn]);
    cur ^= 1;
  }
#undef STAGE_GEMM

  for (int fm = 0; fm < 4; fm++)
    for (int fn = 0; fn < 4; fn++)
      for (int r = 0; r < 4; r++) {
        int gm = m0 + wm * 64 + fm * 16 + quad * 4 + r;
        int gn = n0 + wn * 64 + fn * 16 + l16;
        float val = acc[fm][fn][r] * scale;
        if (MODE == 0) {
          int b = gm >> 11, s = gm & 2047;
          int h = gn >> 6,  d = gn & 63;
          ((unsigned short*)Cout)[((size_t)((b * H_ + h) * S_ + s) << 6) + d] = f2bf(val);
        } else if (MODE == 1) {
          ((float*)Cout)[((size_t)gm << 10) + gn] = val;
        } else {
          int b = gm >> 11, s = gm & 2047;
          int h = gn >> 6,  d = gn & 63;
          int p = ((s & 63) >> 4) + (s & 15) * 4;   // inv_sigma within 64-block
          ((unsigned short*)Cout)[(((size_t)(b * H_ + h) * 64 + d) << 11) + (s & ~63) + p] = f2bf(val);
        }
      }
}

// ---------------------------------------------------------------------------
// Flash attention v4: no-max exp2 softmax, V pre-transposed+sigma-permuted
// ([B,H,64,S]), K and V^T staged via XOR-swizzled global_load_lds.
// Double-buffered K/V LDS, one barrier per iter; raw v_exp_f32.
// ---------------------------------------------------------------------------
__global__ __launch_bounds__(512, 4) void attn_kernel(const unsigned short* __restrict__ q,
                                                      const unsigned short* __restrict__ k,
                                                      const unsigned short* __restrict__ vT,
                                                      unsigned short* __restrict__ X) {
  __shared__ unsigned short Ks[2][64 * 64];   // 2 x 8 KB, XOR-swizzled chunks
  __shared__ unsigned short Vt[2][64 * 64];   // 2 x 8 KB, XOR-swizzled chunks
  __shared__ unsigned short Ps[8][16 * 72];   // 18 KB, per-wave P tile, padded

  const int tid  = threadIdx.x;
  const int wave = tid >> 6, lane = tid & 63;
  const int quad = lane >> 4, l16 = lane & 15;
  // XCD-aware remap (bijective on 8x64 grid)
  const int bh = blockIdx.x * 8 + (blockIdx.y >> 3);
  const int q0 = (blockIdx.y & 7) * 256;

  const unsigned short* qh = q  + (size_t)bh * S_ * 64;
  const unsigned short* kh = k  + (size_t)bh * S_ * 64;
  const unsigned short* vh = vT + (size_t)bh * 64 * S_;   // [d][s']

  // staging pattern: 512 lanes x 16B = full 8 KB tile; chunk c of row r at
  // slot c^(r&7)
  const int sr  = tid >> 3;
  const int sgc = (tid & 7) ^ (sr & 7);

  // Q fragments (A-layout), resident: 2 qt x 2 k-chunks
  short8 qf[2][2];
  for (int qt = 0; qt < 2; qt++) {
    int row = q0 + wave * 32 + qt * 16 + l16;
    for (int kk = 0; kk < 2; kk++)
      qf[qt][kk] = *(const short8*)(qh + (size_t)row * 64 + kk * 32 + quad * 8);
  }

  // ones-column B-frag: B[k][n] = (n==0) ? 1 : 0
  short8 onesb = {};
  if (l16 == 0)
    for (int e = 0; e < 8; e++) onesb[e] = (short)0x3F80;

  const floatx4 fz = {};   // hoisted zero for per-iter score accumulators
  floatx4 O[2][4] = {};
  floatx4 lacc[2] = {};

  // prologue: stage tile 0 into buffer 0
  gload_lds16(kh + (size_t)sr * 64 + sgc * 8,       Ks[0] + (size_t)(wave * 64) * 8);
  gload_lds16(vh + (size_t)sr * S_ + 0 + sgc * 8,   Vt[0] + (size_t)(wave * 64) * 8);

  int cur = 0;
  for (int j0 = 0; j0 < S_; j0 += 64) {
    // One barrier per iter: drains last iter's loads (covered by the whole
    // compute phase) and orders reads of buf[cur^1] before its overwrite.
    __syncthreads();

    // issue next tile's stage early (overlaps with this iter's compute)
    if (j0 + 64 < S_) {
      int nxt = cur ^ 1;
      gload_lds16(kh + (size_t)(j0 + 64 + sr) * 64 + sgc * 8,
                  Ks[nxt] + (size_t)(wave * 64) * 8);
      gload_lds16(vh + (size_t)sr * S_ + (j0 + 64) + sgc * 8,
                  Vt[nxt] + (size_t)(wave * 64) * 8);
    }

    // K frags (B-layout: n=j=jf*16+l16, k=d): undo swizzle
    short8 kf[4][2];
    for (int jf = 0; jf < 4; jf++)
      for (int kk = 0; kk < 2; kk++) {
        int sl = (kk * 4 + quad) ^ (l16 & 7);
        kf[jf][kk] = *(const short8*)(Ks[cur] + (jf * 16 + l16) * 64 + sl * 8);
      }

    unsigned short* pw = Ps[wave];
    short8 pa[2][2];
    for (int qt = 0; qt < 2; qt++) {
      floatx4 s[4];
      for (int jf = 0; jf < 4; jf++) {
        s[jf] = mfma_bf16(qf[qt][0], kf[jf][0], fz);
        s[jf] = mfma_bf16(qf[qt][1], kf[jf][1], s[jf]);
      }
      // p = exp2(score) (q pre-scaled by log2e/sqrt(dk)); raw v_exp_f32,
      // RTZ-pack to bf16. Lane's 4 jf-values land at sigma positions 4*l16+jf.
      for (int r = 0; r < 4; r++) {
        float e0 = __builtin_amdgcn_exp2f(s[0][r]);
        float e1 = __builtin_amdgcn_exp2f(s[1][r]);
        float e2 = __builtin_amdgcn_exp2f(s[2][r]);
        float e3 = __builtin_amdgcn_exp2f(s[3][r]);
        uint2 pk;
        pk.x = pack_bf2(e0, e1);
        pk.y = pack_bf2(e2, e3);
        *(uint2*)(pw + (quad * 4 + r) * 72 + l16 * 4) = pk;
      }
      pa[qt][0] = *(const short8*)(pw + l16 * 72 + quad * 8);
      pa[qt][1] = *(const short8*)(pw + l16 * 72 + 32 + quad * 8);
      lacc[qt] = mfma_bf16(pa[qt][0], onesb, lacc[qt]);
      lacc[qt] = mfma_bf16(pa[qt][1], onesb, lacc[qt]);
    }

    // PV: V frags loaded per-df (8 VGPRs live at a time)
    for (int df = 0; df < 4; df++) {
      int sl0 = quad ^ (l16 & 7);
      int sl1 = (4 + quad) ^ (l16 & 7);
      short8 v0 = *(const short8*)(Vt[cur] + (df * 16 + l16) * 64 + sl0 * 8);
      short8 v1 = *(const short8*)(Vt[cur] + (df * 16 + l16) * 64 + sl1 * 8);
      for (int qt = 0; qt < 2; qt++) {
        O[qt][df] = mfma_bf16(pa[qt][0], v0, O[qt][df]);
        O[qt][df] = mfma_bf16(pa[qt][1], v1, O[qt][df]);
      }
    }
    cur ^= 1;
  }

  // epilogue: l lives in lane quad*16 (col 0), reg r; broadcast, divide, store
  const int b = bh >> 4, h = bh & 15;
  for (int qt = 0; qt < 2; qt++)
    for (int r = 0; r < 4; r++) {
      float lsum = __shfl(lacc[qt][r], (lane & 48));
      float inv = 1.0f / lsum;
      int row = q0 + wave * 32 + qt * 16 + quad * 4 + r;
      unsigned short* dst = X + ((size_t)(b * S_ + row) << 10) + h * 64;
      for (int df = 0; df < 4; df++)
        dst[df * 16 + l16] = f2bf(O[qt][df][r] * inv);
    }
}

// ---------------------------------------------------------------------------
extern "C" void kernel_launch(void* const* d_in, const int* in_sizes, int n_in,
                              void* d_out, int out_size, void* d_ws, size_t ws_size,
                              hipStream_t stream) {
  const float* Q  = (const float*)d_in[0];
  const float* K  = (const float*)d_in[1];
  const float* V  = (const float*)d_in[2];
  const float* wq = (const float*)d_in[3];
  const float* wk = (const float*)d_in[4];
  const float* wv = (const float*)d_in[5];
  const float* wo = (const float*)d_in[6];

  char* ws = (char*)d_ws;
  unsigned short* buf0 = (unsigned short*)ws;                        // 16 MB (attn X)
  unsigned short* wqT  = (unsigned short*)(ws + (size_t)(16 << 20));
  unsigned short* wkT  = (unsigned short*)(ws + (size_t)(18 << 20));
  unsigned short* wvT  = (unsigned short*)(ws + (size_t)(20 << 20));
  unsigned short* woT  = (unsigned short*)(ws + (size_t)(22 << 20));
  unsigned short* qP   = (unsigned short*)(ws + (size_t)(24 << 20));  // [B,H,S,64]
  unsigned short* kP   = (unsigned short*)(ws + (size_t)(40 << 20));  // [B,H,S,64]
  unsigned short* vTg  = (unsigned short*)(ws + (size_t)(56 << 20));  // [B,H,64,S] sigma

  const float SC = 0.18033688011112043f;   // log2(e) / sqrt(64), folded into q

  wt_kernel<<<dim3(16, 16, 4), dim3(256), 0, stream>>>(wq, wk, wv, wo, wqT, wkT, wvT, woT);

  proj_kernel<<<dim3(8, 64, 3), dim3(256), 0, stream>>>(Q, K, V, wqT, wkT, wvT,
                                                        qP, kP, vTg, SC);

  attn_kernel<<<dim3(8, 64), dim3(512), 0, stream>>>(qP, kP, vTg, buf0);

  gemm_bt_kernel<1><<<dim3(8, 64), dim3(256), 0, stream>>>(buf0, woT, (float*)d_out, 1.0f);
}